// Round 5
// baseline (74.077 us; speedup 1.0000x reference)
//
#include <hip/hip_runtime.h>
#include <math.h>

// Problem geometry (from reference):
//   p3: x-count 100, y-count 152, stride 8  -> 45600 anchors
//   p4: x-count 50,  y-count 76,  stride 16 -> 11400 anchors
//   p5: x-count 25,  y-count 38,  stride 32 ->  2850 anchors
// within-level anchor index: ((i*hx + j)*3 + r), i = y idx, j = x idx
// outputs flat: boxes[59850*4] | anchors[59850*4] | max_iou[59850]
#define NTOT     59850
#define NPROP    2000
#define ANCH_OFF 239400   // floats
#define MIOU_OFF 478800   // floats
#define NCHUNK   32
#define CS       64       // 32*64 = 2048 >= 2000 (clamped dups harmless for max)
#define IOU_GX   8        // 8*1024 = 8192 worklist slots per sweep (expect ~7K)

// d_ws layout (uint words): [0..3] bbox keys (min-x,min-y as key(-v); max-x,max-y
// as key(v)), [4] live count, [8..] live anchor id list (byte offset 32)

struct BuildConsts {
    float hw[3][3];   // half-width  [level][aspect]
    float hh[3][3];   // half-height [level][aspect]
    float clampv;     // log(224/8)
};

// monotone signed-float <-> uint key: f1 < f2  <=>  fkey(f1) < fkey(f2)
__device__ __forceinline__ unsigned fkey(float f) {
    unsigned u = __float_as_uint(f);
    return (u & 0x80000000u) ? ~u : (u | 0x80000000u);
}
__device__ __forceinline__ float funkey(unsigned k) {
    return __uint_as_float((k & 0x80000000u) ? (k & 0x7fffffffu) : ~k);
}

// shared by build_kernel and iou_kernel so proposals match boxes bit-for-bit
__device__ __forceinline__ float4 make_box(float x, float y, float hwv, float hhv,
                                           float4 d, float clampv)
{
    float ax0 = x - hwv, ay0 = y - hhv;
    float ax1 = x + hwv, ay1 = y + hhv;
    float w  = ax1 - ax0, h = ay1 - ay0;
    float cx = (ax0 + ax1) * 0.5f, cy = (ay0 + ay1) * 0.5f;
    float dwx = fminf(d.z, clampv), dwy = fminf(d.w, clampv);
    float ncx = cx + w * d.x, ncy = cy + h * d.y;
    float nw  = w * expf(dwx), nh = h * expf(dwy);
    return make_float4(ncx - 0.5f * nw, ncy - 0.5f * nh,
                       ncx + 0.5f * nw, ncy + 0.5f * nh);
}

// analytic anchor from global id (pure index math, no loads)
__device__ __forceinline__ void anchor_from_id(int g, const BuildConsts& C,
    float& x, float& y, float& hwv, float& hhv)
{
    int lev, a, hx; float s;
    if (g < 45600)      { lev = 0; a = g;         hx = 100; s = 8.f;  }
    else if (g < 57000) { lev = 1; a = g - 45600; hx = 50;  s = 16.f; }
    else                { lev = 2; a = g - 57000; hx = 25;  s = 32.f; }
    int loc = a / 3, r = a - loc * 3;
    int i = loc / hx, j = loc - i * hx;
    x = s * ((float)j + 0.5f);
    y = s * ((float)i + 0.5f);
    hwv = C.hw[lev][r]; hhv = C.hh[lev][r];
}

__global__ __launch_bounds__(256) void build_kernel(
    const float4* __restrict__ d3,
    const float4* __restrict__ d4,
    const float4* __restrict__ d5,
    float* __restrict__ out,
    unsigned* __restrict__ bbox_keys,
    BuildConsts C)
{
    int g = blockIdx.x * 256 + threadIdx.x;
    if (g >= NTOT) return;

    const float4* dl; int a;
    if (g < 45600)      { dl = d3; a = g; }
    else if (g < 57000) { dl = d4; a = g - 45600; }
    else                { dl = d5; a = g - 57000; }

    float x, y, hwv, hhv;
    anchor_from_id(g, C, x, y, hwv, hhv);

    float4 b = make_box(x, y, hwv, hhv, dl[a], C.clampv);
    ((float4*)out)[g] = b;
    ((float4*)(out + ANCH_OFF))[g] = make_float4(x - hwv, y - hhv, x + hwv, y + hhv);
    out[MIOU_OFF + g] = 0.0f;   // re-zero every call (replays don't re-poison)

    // blocks 0..7 hold all g < 2000: reduce the proposal-union bbox
    if (blockIdx.x < 8) {
        bool isp = (g < NPROP);
        float nx0 = isp ? -b.x : -1e30f;   // negated: max(-x0) = -min(x0)
        float ny0 = isp ? -b.y : -1e30f;
        float px1 = isp ?  b.z : -1e30f;
        float py1 = isp ?  b.w : -1e30f;
        #pragma unroll
        for (int m = 32; m; m >>= 1) {
            nx0 = fmaxf(nx0, __shfl_xor(nx0, m));
            ny0 = fmaxf(ny0, __shfl_xor(ny0, m));
            px1 = fmaxf(px1, __shfl_xor(px1, m));
            py1 = fmaxf(py1, __shfl_xor(py1, m));
        }
        if ((threadIdx.x & 63) == 0) {
            atomicMax(&bbox_keys[0], fkey(nx0));
            atomicMax(&bbox_keys[1], fkey(ny0));
            atomicMax(&bbox_keys[2], fkey(px1));
            atomicMax(&bbox_keys[3], fkey(py1));
        }
    }
}

// ballot-compact live anchor ids (overlap proposal-union bbox) into worklist
__global__ __launch_bounds__(256) void compact_kernel(
    const unsigned* __restrict__ bbox_keys,
    unsigned* __restrict__ cnt,
    int* __restrict__ list,
    BuildConsts C)
{
    int g = blockIdx.x * 256 + threadIdx.x;
    bool live = false;
    if (g < NTOT) {
        float x, y, hwv, hhv;
        anchor_from_id(g, C, x, y, hwv, hhv);
        float bx0 = -funkey(bbox_keys[0]);
        float by0 = -funkey(bbox_keys[1]);
        float bx1 =  funkey(bbox_keys[2]);
        float by1 =  funkey(bbox_keys[3]);
        live = (x - hwv) <= bx1 && (x + hwv) >= bx0 &&
               (y - hhv) <= by1 && (y + hhv) >= by0;
    }
    unsigned long long bal = __ballot((int)live);
    int lane = threadIdx.x & 63;
    unsigned off = 0;
    if (lane == 0 && bal) off = atomicAdd(cnt, (unsigned)__popcll(bal));
    off = (unsigned)__shfl((int)off, 0);
    if (live) list[off + __popcll(bal & ((1ull << lane) - 1ull))] = g;
}

// grid (IOU_GX, 32): grid-stride over the worklist (4 anchors/thread),
// y = proposal chunk of 64 recomputed from deltas_p3.
__global__ __launch_bounds__(256) void iou_kernel(
    const float4* __restrict__ d3,
    const float4* __restrict__ anch,
    const unsigned* __restrict__ cnt,
    const int* __restrict__ list,
    float* __restrict__ miou,
    BuildConsts C)
{
    __shared__ float4 Pb[CS];
    __shared__ float  Pa[CS];
    __shared__ float4 bbS;

    int tid = threadIdx.x;
    if (tid < CS) {
        int p = blockIdx.y * CS + tid;
        p = p < NPROP ? p : NPROP - 1;   // clamp: duplicate is harmless for max
        int loc = p / 3, r = p - loc * 3;
        int i = loc / 100, j = loc - i * 100;
        float x = 8.0f * ((float)j + 0.5f);
        float y = 8.0f * ((float)i + 0.5f);
        float4 b = make_box(x, y, C.hw[0][r], C.hh[0][r], d3[p], C.clampv);
        Pb[tid] = b;
        Pa[tid] = (b.z - b.x) * (b.w - b.y);
        float bx0 = b.x, by0 = b.y, bx1 = b.z, by1 = b.w;
        #pragma unroll
        for (int m = 32; m; m >>= 1) {
            bx0 = fminf(bx0, __shfl_xor(bx0, m));
            by0 = fminf(by0, __shfl_xor(by0, m));
            bx1 = fmaxf(bx1, __shfl_xor(bx1, m));
            by1 = fmaxf(by1, __shfl_xor(by1, m));
        }
        if (tid == 0) bbS = make_float4(bx0, by0, bx1, by1);
    }
    __syncthreads();
    float4 bb = bbS;
    int L = (int)*cnt;

    for (int ab = blockIdx.x; ab * 1024 < L; ab += IOU_GX) {
        int base = ab * 1024 + tid;
        float ax0[4], ay0[4], ax1[4], ay1[4], a2[4], Ib[4], Sb[4];
        int   idv[4];
        bool  any = false;
        #pragma unroll
        for (int k = 0; k < 4; ++k) {
            int pos = base + k * 256;
            int id  = (pos < L) ? list[pos] : 0;   // dup of a live id: harmless
            idv[k]  = id;
            float4 A = anch[id];
            ax0[k] = A.x; ay0[k] = A.y; ax1[k] = A.z; ay1[k] = A.w;
            a2[k]  = (A.z - A.x) * (A.w - A.y);
            Ib[k]  = 0.0f; Sb[k] = 1.0f;
            any = any || (A.x <= bb.z && A.z >= bb.x &&
                          A.y <= bb.w && A.w >= bb.y);
        }
        if (__any((int)any)) {
            #pragma unroll 2
            for (int p = 0; p < CS; ++p) {
                float4 b  = Pb[p];   // broadcast read, conflict-free
                float  pa = Pa[p];
                #pragma unroll
                for (int k = 0; k < 4; ++k) {
                    float xl = fmaxf(b.x, ax0[k]);
                    float yl = fmaxf(b.y, ay0[k]);
                    float xr = fminf(b.z, ax1[k]);
                    float yr = fminf(b.w, ay1[k]);
                    float iw = fmaxf(xr - xl, 0.0f);
                    float ih = fmaxf(yr - yl, 0.0f);
                    float inter = iw * ih;
                    float S = pa + a2[k];
                    // IoU_a > IoU_b  <=>  Ia*Sb > Ib*Sa  (S = sum of areas)
                    bool better = inter * Sb[k] > Ib[k] * S;
                    Ib[k] = better ? inter : Ib[k];
                    Sb[k] = better ? S     : Sb[k];
                }
            }
        }
        #pragma unroll
        for (int k = 0; k < 4; ++k) {
            if (Ib[k] > 0.0f) {
                float m = Ib[k] / (Sb[k] - Ib[k]);
                // IoU >= 0: uint compare == float compare; max order-independent
                atomicMax((unsigned int*)(miou + idv[k]), __float_as_uint(m));
            }
        }
    }
}

extern "C" void kernel_launch(void* const* d_in, const int* in_sizes, int n_in,
                              void* d_out, int out_size, void* d_ws, size_t ws_size,
                              hipStream_t stream) {
    // inputs: 0..2 = feats (unused), 3..5 = deltas p3/p4/p5
    const float4* d3 = (const float4*)d_in[3];
    const float4* d4 = (const float4*)d_in[4];
    const float4* d5 = (const float4*)d_in[5];
    float* out = (float*)d_out;
    unsigned* ws_u = (unsigned*)d_ws;

    BuildConsts C;
    const double sArr[3]  = {8.0, 16.0, 32.0};
    const double arArr[3] = {0.5, 1.0, 2.0};
    for (int l = 0; l < 3; ++l) {
        double as   = 4.0 * sArr[l];
        double area = as * as;
        for (int rr = 0; rr < 3; ++rr) {
            double w = sqrt(area / arArr[rr]);
            double h = area / w;
            C.hw[l][rr] = (float)w * 0.5f;
            C.hh[l][rr] = (float)h * 0.5f;
        }
    }
    C.clampv = (float)log(224.0 / 8.0);

    // zero bbox keys (key 0 = -inf-most) + live count, every call
    hipMemsetAsync(d_ws, 0, 20, stream);
    build_kernel<<<dim3((NTOT + 255) / 256), 256, 0, stream>>>(
        d3, d4, d5, out, ws_u, C);
    compact_kernel<<<dim3((NTOT + 255) / 256), 256, 0, stream>>>(
        ws_u, ws_u + 4, (int*)d_ws + 8, C);
    iou_kernel<<<dim3(IOU_GX, NCHUNK), 256, 0, stream>>>(
        d3, (const float4*)(out + ANCH_OFF), ws_u + 4,
        (const int*)d_ws + 8, out + MIOU_OFF, C);
}

// Round 6
// 33.623 us; speedup vs baseline: 2.2031x; 2.2031x over previous
//
#include <hip/hip_runtime.h>
#include <math.h>

// Problem geometry (from reference):
//   p3: x-count 100, y-count 152, stride 8  -> 45600 anchors
//   p4: x-count 50,  y-count 76,  stride 16 -> 11400 anchors
//   p5: x-count 25,  y-count 38,  stride 32 ->  2850 anchors
// within-level anchor index: ((i*hx + j)*3 + r), i = y idx, j = x idx
// outputs flat: boxes[59850*4] | anchors[59850*4] | max_iou[59850]
#define NTOT     59850
#define NPROP    2000
#define ANCH_OFF 239400   // floats
#define MIOU_OFF 478800   // floats
#define NCHUNK   32
#define CS       64       // 32*64 = 2048 >= 2000 (clamped dups harmless for max)
#define IOU_GX   8        // 8*1024 = 8192 worklist slots per sweep (expect ~8K)

// d_ws layout (uint words): [0..3] bbox keys (min-x,min-y as key(-v); max-x,max-y
// as key(v)), [4] live count, [8..] live anchor id list (byte offset 32)

struct BuildConsts {
    float hw[3][3];   // half-width  [level][aspect]
    float hh[3][3];   // half-height [level][aspect]
    float clampv;     // log(224/8)
};

// monotone signed-float <-> uint key: f1 < f2  <=>  fkey(f1) < fkey(f2)
__device__ __forceinline__ unsigned fkey(float f) {
    unsigned u = __float_as_uint(f);
    return (u & 0x80000000u) ? ~u : (u | 0x80000000u);
}
__device__ __forceinline__ float funkey(unsigned k) {
    return __uint_as_float((k & 0x80000000u) ? (k & 0x7fffffffu) : ~k);
}

// shared by build_kernel and iou_kernel so proposals match boxes bit-for-bit
__device__ __forceinline__ float4 make_box(float x, float y, float hwv, float hhv,
                                           float4 d, float clampv)
{
    float ax0 = x - hwv, ay0 = y - hhv;
    float ax1 = x + hwv, ay1 = y + hhv;
    float w  = ax1 - ax0, h = ay1 - ay0;
    float cx = (ax0 + ax1) * 0.5f, cy = (ay0 + ay1) * 0.5f;
    float dwx = fminf(d.z, clampv), dwy = fminf(d.w, clampv);
    float ncx = cx + w * d.x, ncy = cy + h * d.y;
    float nw  = w * expf(dwx), nh = h * expf(dwy);
    return make_float4(ncx - 0.5f * nw, ncy - 0.5f * nh,
                       ncx + 0.5f * nw, ncy + 0.5f * nh);
}

// analytic anchor from global id (pure index math, no loads)
__device__ __forceinline__ void anchor_from_id(int g, const BuildConsts& C,
    float& x, float& y, float& hwv, float& hhv)
{
    int lev, a, hx; float s;
    if (g < 45600)      { lev = 0; a = g;         hx = 100; s = 8.f;  }
    else if (g < 57000) { lev = 1; a = g - 45600; hx = 50;  s = 16.f; }
    else                { lev = 2; a = g - 57000; hx = 25;  s = 32.f; }
    int loc = a / 3, r = a - loc * 3;
    int i = loc / hx, j = loc - i * hx;
    x = s * ((float)j + 0.5f);
    y = s * ((float)i + 0.5f);
    hwv = C.hw[lev][r]; hhv = C.hh[lev][r];
}

__global__ __launch_bounds__(256) void build_kernel(
    const float4* __restrict__ d3,
    const float4* __restrict__ d4,
    const float4* __restrict__ d5,
    float* __restrict__ out,
    unsigned* __restrict__ bbox_keys,
    BuildConsts C)
{
    int g = blockIdx.x * 256 + threadIdx.x;
    if (g >= NTOT) return;

    const float4* dl; int a;
    if (g < 45600)      { dl = d3; a = g; }
    else if (g < 57000) { dl = d4; a = g - 45600; }
    else                { dl = d5; a = g - 57000; }

    float x, y, hwv, hhv;
    anchor_from_id(g, C, x, y, hwv, hhv);

    float4 b = make_box(x, y, hwv, hhv, dl[a], C.clampv);
    ((float4*)out)[g] = b;
    ((float4*)(out + ANCH_OFF))[g] = make_float4(x - hwv, y - hhv, x + hwv, y + hhv);
    out[MIOU_OFF + g] = 0.0f;   // re-zero every call (replays don't re-poison)

    // blocks 0..7 hold all g < 2000: reduce the proposal-union bbox
    if (blockIdx.x < 8) {
        bool isp = (g < NPROP);
        float nx0 = isp ? -b.x : -1e30f;   // negated: max(-x0) = -min(x0)
        float ny0 = isp ? -b.y : -1e30f;
        float px1 = isp ?  b.z : -1e30f;
        float py1 = isp ?  b.w : -1e30f;
        #pragma unroll
        for (int m = 32; m; m >>= 1) {
            nx0 = fmaxf(nx0, __shfl_xor(nx0, m));
            ny0 = fmaxf(ny0, __shfl_xor(ny0, m));
            px1 = fmaxf(px1, __shfl_xor(px1, m));
            py1 = fmaxf(py1, __shfl_xor(py1, m));
        }
        if ((threadIdx.x & 63) == 0) {
            atomicMax(&bbox_keys[0], fkey(nx0));
            atomicMax(&bbox_keys[1], fkey(ny0));
            atomicMax(&bbox_keys[2], fkey(px1));
            atomicMax(&bbox_keys[3], fkey(py1));
        }
    }
}

// ballot-compact live anchor ids (overlap proposal-union bbox) into worklist
__global__ __launch_bounds__(256) void compact_kernel(
    const unsigned* __restrict__ bbox_keys,
    unsigned* __restrict__ cnt,
    int* __restrict__ list,
    BuildConsts C)
{
    int g = blockIdx.x * 256 + threadIdx.x;
    bool live = false;
    if (g < NTOT) {
        float x, y, hwv, hhv;
        anchor_from_id(g, C, x, y, hwv, hhv);
        float bx0 = -funkey(bbox_keys[0]);
        float by0 = -funkey(bbox_keys[1]);
        float bx1 =  funkey(bbox_keys[2]);
        float by1 =  funkey(bbox_keys[3]);
        live = (x - hwv) <= bx1 && (x + hwv) >= bx0 &&
               (y - hhv) <= by1 && (y + hhv) >= by0;
    }
    unsigned long long bal = __ballot((int)live);
    int lane = threadIdx.x & 63;
    unsigned off = 0;
    if (lane == 0 && bal) off = atomicAdd(cnt, (unsigned)__popcll(bal));
    off = (unsigned)__shfl((int)off, 0);
    if (live) list[off + __popcll(bal & ((1ull << lane) - 1ull))] = g;
}

// grid (IOU_GX, 32): grid-stride over the worklist (4 anchors/thread),
// y = proposal chunk of 64 recomputed from deltas_p3.
__global__ __launch_bounds__(256) void iou_kernel(
    const float4* __restrict__ d3,
    const float4* __restrict__ anch,
    const unsigned* __restrict__ cnt,
    const int* __restrict__ list,
    float* __restrict__ miou,
    BuildConsts C)
{
    __shared__ float4 Pb[CS];
    __shared__ float  Pa[CS];
    __shared__ float4 bbS;

    int tid = threadIdx.x;
    if (tid < CS) {
        int p = blockIdx.y * CS + tid;
        p = p < NPROP ? p : NPROP - 1;   // clamp: duplicate is harmless for max
        int loc = p / 3, r = p - loc * 3;
        int i = loc / 100, j = loc - i * 100;
        float x = 8.0f * ((float)j + 0.5f);
        float y = 8.0f * ((float)i + 0.5f);
        float4 b = make_box(x, y, C.hw[0][r], C.hh[0][r], d3[p], C.clampv);
        Pb[tid] = b;
        Pa[tid] = (b.z - b.x) * (b.w - b.y);
        float bx0 = b.x, by0 = b.y, bx1 = b.z, by1 = b.w;
        #pragma unroll
        for (int m = 32; m; m >>= 1) {
            bx0 = fminf(bx0, __shfl_xor(bx0, m));
            by0 = fminf(by0, __shfl_xor(by0, m));
            bx1 = fmaxf(bx1, __shfl_xor(bx1, m));
            by1 = fmaxf(by1, __shfl_xor(by1, m));
        }
        if (tid == 0) bbS = make_float4(bx0, by0, bx1, by1);
    }
    __syncthreads();
    float4 bb = bbS;
    int L = (int)*cnt;

    for (int ab = blockIdx.x; ab * 1024 < L; ab += IOU_GX) {
        int base = ab * 1024 + tid;
        float ax0[4], ay0[4], ax1[4], ay1[4], a2[4], Ib[4], Sb[4];
        int   idv[4];
        bool  val[4];
        bool  any = false;
        #pragma unroll
        for (int k = 0; k < 4; ++k) {
            int pos = base + k * 256;
            val[k]  = (pos < L);
            int id  = val[k] ? list[pos] : 0;
            idv[k]  = id;
            float4 A = anch[id];
            ax0[k] = A.x; ay0[k] = A.y; ax1[k] = A.z; ay1[k] = A.w;
            a2[k]  = (A.z - A.x) * (A.w - A.y);
            Ib[k]  = 0.0f; Sb[k] = 1.0f;
            // pad lanes (val=false) must NOT wake the block or emit atomics:
            // round-5 bug was ~9K serialized atomicMax ops on miou[0] = 55 us
            any = any || (val[k] && A.x <= bb.z && A.z >= bb.x &&
                          A.y <= bb.w && A.w >= bb.y);
        }
        if (__any((int)any)) {
            #pragma unroll 2
            for (int p = 0; p < CS; ++p) {
                float4 b  = Pb[p];   // broadcast read, conflict-free
                float  pa = Pa[p];
                #pragma unroll
                for (int k = 0; k < 4; ++k) {
                    float xl = fmaxf(b.x, ax0[k]);
                    float yl = fmaxf(b.y, ay0[k]);
                    float xr = fminf(b.z, ax1[k]);
                    float yr = fminf(b.w, ay1[k]);
                    float iw = fmaxf(xr - xl, 0.0f);
                    float ih = fmaxf(yr - yl, 0.0f);
                    float inter = iw * ih;
                    float S = pa + a2[k];
                    // IoU_a > IoU_b  <=>  Ia*Sb > Ib*Sa  (S = sum of areas)
                    bool better = inter * Sb[k] > Ib[k] * S;
                    Ib[k] = better ? inter : Ib[k];
                    Sb[k] = better ? S     : Sb[k];
                }
            }
        }
        #pragma unroll
        for (int k = 0; k < 4; ++k) {
            if (val[k] && Ib[k] > 0.0f) {
                float m = Ib[k] / (Sb[k] - Ib[k]);
                // IoU >= 0: uint compare == float compare; max order-independent
                atomicMax((unsigned int*)(miou + idv[k]), __float_as_uint(m));
            }
        }
    }
}

extern "C" void kernel_launch(void* const* d_in, const int* in_sizes, int n_in,
                              void* d_out, int out_size, void* d_ws, size_t ws_size,
                              hipStream_t stream) {
    // inputs: 0..2 = feats (unused), 3..5 = deltas p3/p4/p5
    const float4* d3 = (const float4*)d_in[3];
    const float4* d4 = (const float4*)d_in[4];
    const float4* d5 = (const float4*)d_in[5];
    float* out = (float*)d_out;
    unsigned* ws_u = (unsigned*)d_ws;

    BuildConsts C;
    const double sArr[3]  = {8.0, 16.0, 32.0};
    const double arArr[3] = {0.5, 1.0, 2.0};
    for (int l = 0; l < 3; ++l) {
        double as   = 4.0 * sArr[l];
        double area = as * as;
        for (int rr = 0; rr < 3; ++rr) {
            double w = sqrt(area / arArr[rr]);
            double h = area / w;
            C.hw[l][rr] = (float)w * 0.5f;
            C.hh[l][rr] = (float)h * 0.5f;
        }
    }
    C.clampv = (float)log(224.0 / 8.0);

    // zero bbox keys (key 0 = -inf-most) + live count, every call
    hipMemsetAsync(d_ws, 0, 20, stream);
    build_kernel<<<dim3((NTOT + 255) / 256), 256, 0, stream>>>(
        d3, d4, d5, out, ws_u, C);
    compact_kernel<<<dim3((NTOT + 255) / 256), 256, 0, stream>>>(
        ws_u, ws_u + 4, (int*)d_ws + 8, C);
    iou_kernel<<<dim3(IOU_GX, NCHUNK), 256, 0, stream>>>(
        d3, (const float4*)(out + ANCH_OFF), ws_u + 4,
        (const int*)d_ws + 8, out + MIOU_OFF, C);
}